// Round 5
// baseline (123.274 us; speedup 1.0000x reference)
//
#include <hip/hip_runtime.h>
#include <hip/hip_bf16.h>

// BatchIrregularDownsample2d (D=2): out[b,c,j] = in[b,c,G[b,j]]
// R5: region-split kernels with row-uniform 2D grid (blockIdx.y = row).
//  - prefix_kernel: pure copy region j < start  (scalar hdr, no division)
//  - tail_kernel:   gather region j >= start (idx quad + 4 gathers)
// Flat output quads stay 16B-aligned; quad ownership = row of first element.

#define HW_FULL 65536
#define T1     1024
#define PER_T  16

typedef float f4a __attribute__((ext_vector_type(4), aligned(4)));
typedef int   i4a __attribute__((ext_vector_type(4), aligned(4)));

__global__ __launch_bounds__(1024) void build_idx_kernel(
    const int* __restrict__ mask, int* __restrict__ hdr, int* __restrict__ gt, int M)
{
    const int b = blockIdx.x;
    const int t = threadIdx.x;
    const int* mb = mask + (long long)b * HW_FULL;

    unsigned char fl[PER_T];
    unsigned long long local = 0ULL;
    #pragma unroll
    for (int k = 0; k < PER_T; ++k) {
        int e = t * PER_T + k;
        int r = e >> 7;
        int c = e & 127;
        int m = mb[(r << 9) + (c << 1)];
        int z  = (m == 0);
        int cs = (m >= 1);
        int dt = (m == 1);
        int tl = ((r | c) & 1) == 0;
        int kl = (tl && (m >= 2)) ? 1 : 0;
        fl[k] = (unsigned char)(z | (cs << 1) | (dt << 2) | (kl << 3));
        local += (unsigned long long)z
               | ((unsigned long long)cs << 16)
               | ((unsigned long long)dt << 32)
               | ((unsigned long long)kl << 48);
    }

    __shared__ unsigned long long sh[T1];
    sh[t] = local;
    __syncthreads();
    for (int off = 1; off < T1; off <<= 1) {
        unsigned long long v = (t >= off) ? sh[t - off] : 0ULL;
        __syncthreads();
        sh[t] += v;
        __syncthreads();
    }
    unsigned long long tot = sh[T1 - 1];
    unsigned long long ex  = (t > 0) ? sh[t - 1] : 0ULL;

    const int zt    = (int)( tot        & 0xFFFF);
    const int ndt   = (int)((tot >> 32) & 0xFFFF);
    const int nkl   = (int)((tot >> 48) & 0xFFFF);
    const int start = zt * 4;

    int csP = (int)((ex >> 16) & 0xFFFF);
    int dtP = (int)((ex >> 32) & 0xFFFF);
    int klP = (int)((ex >> 48) & 0xFFFF);

    int* gtb = gt + (long long)b * M;
    #pragma unroll
    for (int k = 0; k < PER_T; ++k) {
        int f = fl[k];
        if (f & 4) { gtb[dtP]       = start + csP; ++dtP; }
        if (f & 8) { gtb[ndt + klP] = start + csP; ++klP; }
        if (f & 2) { ++csP; }
    }

    if (t == 0) {
        hdr[b * 4 + 0] = start;
        hdr[b * 4 + 1] = ndt;
        hdr[b * 4 + 2] = nkl;
        hdr[b * 4 + 3] = start + ndt + nkl;
    }
}

// Prefix region: out[row*M + j] = in[row*N + j] for j in [0, start).
// One flat-aligned output quad per thread; per-lane 16B (unaligned-ok) load.
__global__ __launch_bounds__(256) void prefix_kernel(
    const float* __restrict__ in, const int* __restrict__ hdr,
    float* __restrict__ out, int N, int M, int cshift)
{
    const int row = blockIdx.y;
    const int b = row >> cshift;                 // wave-uniform -> scalar
    const int start = hdr[b * 4 + 0];

    const long long rowM = (long long)row * (long long)M;
    const long long qlo = (rowM + 3) >> 2;       // first quad owned by this row
    const long long qt0 = (rowM + start) >> 2;   // first non-pure-prefix quad
    const long long q = qlo + (long long)blockIdx.x * 256 + threadIdx.x;
    if (q >= qt0) return;

    const int j = (int)(4 * q - rowM);
    const float* rin = in + (long long)row * (long long)N;
    f4a lv = *reinterpret_cast<const f4a*>(rin + j);
    float4 v = make_float4(lv.x, lv.y, lv.z, lv.w);
    *reinterpret_cast<float4*>(out + 4 * q) = v;
}

// Tail region: quads from the one containing j=start through end of row
// (including the row-boundary straddle quad, which spills into the next
// row's identity prefix).
__global__ __launch_bounds__(256) void tail_kernel(
    const float* __restrict__ in, const int* __restrict__ hdr,
    const int* __restrict__ gt, float* __restrict__ out,
    int N, int M, int cshift, int nrows)
{
    const int row = blockIdx.y;
    const int b = row >> cshift;                 // wave-uniform -> scalar
    const int start = hdr[b * 4 + 0];
    const int len   = hdr[b * 4 + 3];

    const long long rowM = (long long)row * (long long)M;
    const long long qlo  = (rowM + 3) >> 2;
    long long qt0 = (rowM + start) >> 2;
    if (qt0 < qlo) qt0 = qlo;                    // robustness for tiny start
    const long long qend = (rowM + M - 1) >> 2;  // quad containing row's last elem
    const long long q = qt0 + (long long)blockIdx.x * 256 + threadIdx.x;
    if (q > qend) return;

    const long long o = q << 2;
    const int j = (int)(o - rowM);
    const float* rin = in + (long long)row * (long long)N;

    float4 v;
    if (j >= start && j + 3 < len) {
        // fast tail quad: 16B idx load (L2-resident table) + 4 gathers
        i4a idx = *reinterpret_cast<const i4a*>(gt + (long long)b * M + (j - start));
        v = make_float4(rin[idx.x], rin[idx.y], rin[idx.z], rin[idx.w]);
    } else {
        // straddles start, len, or the row boundary: per-element
        float* vf = reinterpret_cast<float*>(&v);
        #pragma unroll
        for (int e = 0; e < 4; ++e) {
            int r2 = row;
            int j2 = j + e;
            if (j2 >= M) { r2 = row + 1; j2 -= M; }
            float x = 0.0f;
            if (r2 < nrows) {
                int b2 = r2 >> cshift;
                int s2 = hdr[b2 * 4 + 0];
                int l2 = hdr[b2 * 4 + 3];
                if (j2 < l2) {
                    int src = (j2 < s2) ? j2
                            : gt[(long long)b2 * M + (j2 - s2)];
                    x = in[(long long)r2 * (long long)N + src];
                }
            }
            vf[e] = x;
        }
    }
    *reinterpret_cast<float4*>(out + o) = v;
}

extern "C" void kernel_launch(void* const* d_in, const int* in_sizes, int n_in,
                              void* d_out, int out_size, void* d_ws, size_t ws_size,
                              hipStream_t stream) {
    const float* x    = (const float*)d_in[0];
    const int*   mask = (const int*)d_in[1];
    float*       out  = (float*)d_out;

    const int B = in_sizes[1] / HW_FULL;          // 8
    const int C = 256;
    const int N = in_sizes[0] / (B * C);          // 32776
    const int M = out_size   / (B * C);           // 28681
    const int nrows = B * C;                      // 2048

    int cshift = 0;
    while ((1 << cshift) < C) ++cshift;

    int* hdr = (int*)d_ws;                        // B*4 ints
    int* gt  = hdr + 32;                          // B*M ints

    build_idx_kernel<<<B, T1, 0, stream>>>(mask, hdr, gt, M);

    // Worst-case quads per row for either region: (M+3)/4 + 1
    const int maxq = (M + 3) / 4 + 1;
    const int gx = (maxq + 255) / 256;            // 29 for M=28681

    dim3 gP(gx, nrows), gT(gx, nrows);
    prefix_kernel<<<gP, 256, 0, stream>>>(x, hdr, out, N, M, cshift);
    tail_kernel  <<<gT, 256, 0, stream>>>(x, hdr, gt, out, N, M, cshift, nrows);
}

// Round 6
// 100.847 us; speedup vs baseline: 1.2224x; 1.2224x over previous
//
#include <hip/hip_runtime.h>
#include <hip/hip_bf16.h>

// BatchIrregularDownsample2d (D=2): out[b,c,j] = in[b,c,G[b,j]]
// R6: - tail gather staged through LDS: dense aligned dwordx4 loads of the
//       cs-region, random reads from LDS, aligned float4 NT stores.
//     - nontemporal stores for all output (keep L3 for input reads).
//     - exact per-row write ownership (head/quads/rem), no straddles.

#define HW_FULL 65536
#define T1     1024
#define PER_T  16
#define CS_CAP 11264   // max staged cs dwords (45 KB LDS)

typedef float f4a __attribute__((ext_vector_type(4), aligned(4)));
typedef float f4v __attribute__((ext_vector_type(4)));
typedef int   i4a __attribute__((ext_vector_type(4), aligned(4)));

__global__ __launch_bounds__(1024) void build_idx_kernel(
    const int* __restrict__ mask, int* __restrict__ hdr, int* __restrict__ gt, int M)
{
    const int b = blockIdx.x;
    const int t = threadIdx.x;
    const int* mb = mask + (long long)b * HW_FULL;

    unsigned char fl[PER_T];
    unsigned long long local = 0ULL;
    #pragma unroll
    for (int k = 0; k < PER_T; ++k) {
        int e = t * PER_T + k;
        int r = e >> 7;
        int c = e & 127;
        int m = mb[(r << 9) + (c << 1)];
        int z  = (m == 0);
        int cs = (m >= 1);
        int dt = (m == 1);
        int tl = ((r | c) & 1) == 0;
        int kl = (tl && (m >= 2)) ? 1 : 0;
        fl[k] = (unsigned char)(z | (cs << 1) | (dt << 2) | (kl << 3));
        local += (unsigned long long)z
               | ((unsigned long long)cs << 16)
               | ((unsigned long long)dt << 32)
               | ((unsigned long long)kl << 48);
    }

    __shared__ unsigned long long sh[T1];
    sh[t] = local;
    __syncthreads();
    for (int off = 1; off < T1; off <<= 1) {
        unsigned long long v = (t >= off) ? sh[t - off] : 0ULL;
        __syncthreads();
        sh[t] += v;
        __syncthreads();
    }
    unsigned long long tot = sh[T1 - 1];
    unsigned long long ex  = (t > 0) ? sh[t - 1] : 0ULL;

    const int zt    = (int)( tot        & 0xFFFF);
    const int cst   = (int)((tot >> 16) & 0xFFFF);
    const int ndt   = (int)((tot >> 32) & 0xFFFF);
    const int nkl   = (int)((tot >> 48) & 0xFFFF);
    const int start = zt * 4;

    int csP = (int)((ex >> 16) & 0xFFFF);
    int dtP = (int)((ex >> 32) & 0xFFFF);
    int klP = (int)((ex >> 48) & 0xFFFF);

    int* gtb = gt + (long long)b * M;
    #pragma unroll
    for (int k = 0; k < PER_T; ++k) {
        int f = fl[k];
        if (f & 4) { gtb[dtP]       = start + csP; ++dtP; }
        if (f & 8) { gtb[ndt + klP] = start + csP; ++klP; }
        if (f & 2) { ++csP; }
    }

    if (t == 0) {
        hdr[b * 4 + 0] = start;
        hdr[b * 4 + 1] = cst;                 // cs region size (N - start)
        hdr[b * 4 + 2] = ndt + nkl;           // ntail
        hdr[b * 4 + 3] = start + ndt + nkl;   // len
    }
}

// Prefix: out[row, 0..start) = in[row, 0..start). Aligned float4 NT stores,
// per-lane contiguous (possibly dword-misaligned) 16B loads. Head/rem partial
// dwords handled by the k==nq edge thread.
__global__ __launch_bounds__(256) void prefix_kernel(
    const float* __restrict__ in, const int* __restrict__ hdr,
    float* __restrict__ out, int N, int M, int cshift)
{
    const int row   = blockIdx.y;
    const int b     = row >> cshift;
    const int start = hdr[b * 4 + 0];
    const long long rowM = (long long)row * M;
    const long long rowN = (long long)row * N;
    const int h  = (int)((4 - (rowM & 3)) & 3);
    const int nq = (start >= h) ? ((start - h) >> 2) : -1;
    const int k  = blockIdx.x * 256 + threadIdx.x;

    const float* rin  = in  + rowN;
    float*       rout = out + rowM;

    if (k < nq) {
        const int j = h + (k << 2);
        f4a lv = *reinterpret_cast<const f4a*>(rin + j);
        f4v v; v.x = lv.x; v.y = lv.y; v.z = lv.z; v.w = lv.w;
        __builtin_nontemporal_store(v, reinterpret_cast<f4v*>(rout + j));
    } else if (k == nq || (nq < 0 && k == 0)) {
        const int hh = (h < start) ? h : start;
        for (int j = 0; j < hh; ++j)
            __builtin_nontemporal_store(rin[j], rout + j);
        if (nq >= 0) {
            const int rem  = (start - h) & 3;
            const int base = h + (nq << 2);
            for (int e = 0; e < rem; ++e)
                __builtin_nontemporal_store(rin[base + e], rout + base + e);
        }
    }
}

// Tail: out[row, start..M). Stage in[row, start..start+cs) densely into LDS,
// gather from LDS, aligned float4 NT stores.
__global__ __launch_bounds__(512) void tail_kernel(
    const float* __restrict__ in, const int* __restrict__ hdr,
    const int* __restrict__ gt, float* __restrict__ out,
    int N, int M, int cshift)
{
    const int row   = blockIdx.x;
    const int b     = row >> cshift;
    const int start = hdr[b * 4 + 0];
    const int csn   = hdr[b * 4 + 1];
    const int ntail = hdr[b * 4 + 2];
    const long long rowM = (long long)row * M;
    const long long rowN = (long long)row * N;
    const int tid = threadIdx.x;

    const float* src  = in + rowN + start;     // dense cs region (16B aligned)
    const int*   gtb  = gt + (long long)b * M;
    float*       rout = out + rowM;

    __shared__ __align__(16) float lds[CS_CAP];
    const bool staged = (csn <= CS_CAP);
    if (staged) {
        const int cs4 = csn & ~3;
        for (int i = tid << 2; i < cs4; i += (512 << 2)) {
            f4a lv = *reinterpret_cast<const f4a*>(src + i);
            f4v* d = reinterpret_cast<f4v*>(&lds[i]);
            f4v v; v.x = lv.x; v.y = lv.y; v.z = lv.z; v.w = lv.w;
            *d = v;
        }
        if (tid < (csn & 3)) lds[cs4 + tid] = src[cs4 + tid];
        __syncthreads();
    }

    const int h2   = (int)((4 - ((rowM + start) & 3)) & 3);
    const int span = M - start;
    const int nq2  = (span >= h2) ? ((span - h2) >> 2) : -1;

    for (int k = tid; k <= nq2 || (nq2 < 0 && k == tid && tid == 0); k += 512) {
        if (k < nq2) {
            const int t = h2 + (k << 2);           // tail-relative index
            const int j = start + t;               // absolute column
            i4a g = *reinterpret_cast<const i4a*>(gtb + t);
            f4v v;
            v.x = (t + 0 < ntail) ? (staged ? lds[g.x - start] : in[rowN + g.x]) : 0.0f;
            v.y = (t + 1 < ntail) ? (staged ? lds[g.y - start] : in[rowN + g.y]) : 0.0f;
            v.z = (t + 2 < ntail) ? (staged ? lds[g.z - start] : in[rowN + g.z]) : 0.0f;
            v.w = (t + 3 < ntail) ? (staged ? lds[g.w - start] : in[rowN + g.w]) : 0.0f;
            __builtin_nontemporal_store(v, reinterpret_cast<f4v*>(rout + j));
        } else if (k == nq2 || nq2 < 0) {
            // edge duties: head dwords + trailing rem dwords
            const int hh = (h2 < span) ? h2 : span;
            for (int e = 0; e < hh; ++e) {
                float x = (e < ntail)
                        ? (staged ? lds[gtb[e] - start] : in[rowN + gtb[e]]) : 0.0f;
                __builtin_nontemporal_store(x, rout + start + e);
            }
            if (nq2 >= 0) {
                const int rem = (span - h2) & 3;
                const int tb  = h2 + (nq2 << 2);
                for (int e = 0; e < rem; ++e) {
                    const int t = tb + e;
                    float x = (t < ntail)
                            ? (staged ? lds[gtb[t] - start] : in[rowN + gtb[t]]) : 0.0f;
                    __builtin_nontemporal_store(x, rout + start + t);
                }
            }
            break;
        }
    }
}

extern "C" void kernel_launch(void* const* d_in, const int* in_sizes, int n_in,
                              void* d_out, int out_size, void* d_ws, size_t ws_size,
                              hipStream_t stream) {
    const float* x    = (const float*)d_in[0];
    const int*   mask = (const int*)d_in[1];
    float*       out  = (float*)d_out;

    const int B = in_sizes[1] / HW_FULL;          // 8
    const int C = 256;
    const int N = in_sizes[0] / (B * C);          // 32776
    const int M = out_size   / (B * C);           // 28681
    const int nrows = B * C;                      // 2048

    int cshift = 0;
    while ((1 << cshift) < C) ++cshift;

    int* hdr = (int*)d_ws;                        // B*4 ints
    int* gt  = hdr + 32;                          // B*M ints

    build_idx_kernel<<<B, T1, 0, stream>>>(mask, hdr, gt, M);

    // Tail first (LDS-heavy, exact 2048 blocks), then the big prefix copy.
    tail_kernel<<<nrows, 512, 0, stream>>>(x, hdr, gt, out, N, M, cshift);

    const int maxq = M / 4 + 1;
    const int gx = (maxq + 255) / 256;            // 29
    dim3 gP(gx, nrows);
    prefix_kernel<<<gP, 256, 0, stream>>>(x, hdr, out, N, M, cshift);
}